// Round 7
// baseline (255.859 us; speedup 1.0000x reference)
//
#include <hip/hip_runtime.h>
#include <math.h>

// Problem constants (T5 encoder self-attention)
#define H_    16
#define S_    2048
#define DH_   64
#define DM_   1024
#define NTOK_ 4096          // B*S
#define NBIAS_ 4095         // 2*S-1 distinct relative positions

typedef __attribute__((ext_vector_type(8))) short short8;  // 8 bf16 (4 VGPRs)
typedef __attribute__((ext_vector_type(4))) float f32x4;   // MFMA C/D frag

#define MFMA16(a, b, c) __builtin_amdgcn_mfma_f32_16x16x32_bf16((a), (b), (c), 0, 0, 0)
#define LOG2E_DIV8 0.18033688011112042f   // 0.125 / ln(2)

__device__ __forceinline__ ushort f2bf(float f) {
  union { float f; unsigned u; } x; x.f = f;
  unsigned r = (x.u + 0x7FFFu + ((x.u >> 16) & 1u)) >> 16;  // RNE
  return (ushort)r;
}

// pack two floats to bf16 pair (round-half-up) in one v_perm: dword = {hi, lo}
__device__ __forceinline__ unsigned bpack(float hi, float lo) {
  union { float f; unsigned u; } a, b;
  a.f = hi; b.f = lo;
  return __builtin_amdgcn_perm(a.u + 0x8000u, b.u + 0x8000u, 0x07060302u);
}

// global (16B per lane) -> LDS at wave-uniform base + lane*16.
__device__ __forceinline__ void ldg16_lds(const ushort* g, ushort* l) {
  __builtin_amdgcn_global_load_lds(
      (const __attribute__((address_space(1))) unsigned int*)g,
      (__attribute__((address_space(3))) unsigned int*)l, 16, 0, 0);
}

// ---------------- fused prep: all fp32->bf16 casts + bias table, ONE dispatch ----------------
// blocks [0,8192): cast X,Wq,Wk,Wv,Wo (compile-time ranges). blocks [8192,8208): bias.
// biasTab stores bias * (1/ln2) so attn can use exp2 with a single fma.
__global__ void prep_k(const float* __restrict__ hs,
                       const float* __restrict__ Wq, const float* __restrict__ Wk,
                       const float* __restrict__ Wv, const float* __restrict__ Wo,
                       const float* __restrict__ rel,
                       ushort* __restrict__ Xb, ushort* __restrict__ Wqb,
                       ushort* __restrict__ Wkb, ushort* __restrict__ Wvb,
                       ushort* __restrict__ Wob, float* __restrict__ biasTab) {
  const int bid = blockIdx.x;
  if (bid < 8192) {
    int i = (bid * 256 + threadIdx.x) * 4;
    const float* src; ushort* dst; int off;
    if (i < 4194304)      { src = hs; dst = Xb;  off = i; }
    else if (i < 5242880) { src = Wq; dst = Wqb; off = i - 4194304; }
    else if (i < 6291456) { src = Wk; dst = Wkb; off = i - 5242880; }
    else if (i < 7340032) { src = Wv; dst = Wvb; off = i - 6291456; }
    else                  { src = Wo; dst = Wob; off = i - 7340032; }
    const float4 v = *(const float4*)(src + off);
    ushort4 o;
    o.x = f2bf(v.x); o.y = f2bf(v.y); o.z = f2bf(v.z); o.w = f2bf(v.w);
    *(ushort4*)(dst + off) = o;
  } else {
    int d = (bid - 8192) * 256 + threadIdx.x;
    if (d >= NBIAS_) return;
    int rp = d - (S_ - 1);
    int ret = (rp > 0) ? 16 : 0;
    int arp = rp < 0 ? -rp : rp;
    int bucket;
    if (arp < 8) {
      bucket = ret + arp;
    } else {
      float t = logf((float)arp * 0.125f);
      t = t / 2.772588722239781f;
      t = t * 8.0f;
      int large = 8 + (int)t;
      if (large > 15) large = 15;
      bucket = ret + large;
    }
    for (int h = 0; h < H_; ++h)
      biasTab[h * NBIAS_ + d] = rel[bucket * H_ + h] * 1.4426950408889634f;
  }
}

// ---------------- shared BK=64 GEMM core: C(128x128) = A @ B^T ----------------
// XOR-swizzled LDS (16B slot ^= row&7): frag ds_read_b128 lands ~2-way (free).
__device__ __forceinline__ void gemm_core(
    const ushort* __restrict__ gA, const ushort* __restrict__ gB,
    ushort* As, ushort* Bs, f32x4 (&acc)[4][4],
    int m0, int n0, int wave, int lane)
{
  const int l15 = lane & 15, quad = lane >> 4;
  const int wm = wave >> 1, wn = wave & 1;
  const int srow = lane >> 3;
  const int sw = ((lane & 7) ^ (lane >> 3)) * 8;   // swizzled source col
  const int px = l15 & 7;

  for (int k0 = 0; k0 < DM_; k0 += 64) {
    __syncthreads();
#pragma unroll
    for (int i = 0; i < 8; ++i) {
      int c = wave * 8 + i;                         // 0..31: 16 A-chunks, 16 B-chunks
      if (c < 16)
        ldg16_lds(gA + (size_t)(m0 + c * 8 + srow) * DM_ + k0 + sw, As + c * 512);
      else
        ldg16_lds(gB + (size_t)(n0 + (c - 16) * 8 + srow) * DM_ + k0 + sw, Bs + (c - 16) * 512);
    }
    __syncthreads();
#pragma unroll
    for (int kk = 0; kk < 2; ++kk) {
      short8 af[4], bfr[4];
#pragma unroll
      for (int mi = 0; mi < 4; ++mi)
        af[mi] = *(const short8*)&As[(wm * 64 + mi * 16 + l15) * 64 + (((kk * 4 + quad) ^ px)) * 8];
#pragma unroll
      for (int ni = 0; ni < 4; ++ni)
        bfr[ni] = *(const short8*)&Bs[(wn * 64 + ni * 16 + l15) * 64 + (((kk * 4 + quad) ^ px)) * 8];
#pragma unroll
      for (int mi = 0; mi < 4; ++mi)
#pragma unroll
        for (int ni = 0; ni < 4; ++ni)
          acc[mi][ni] = MFMA16(af[mi], bfr[ni], acc[mi][ni]);
    }
  }
}

// ---------------- QKV projection ----------------
// z: 0->Q [b,h,s,dh], 1->K [b,h,s,dh], 2->V^T [b,h,dh,s] (via LDS transpose, coalesced)
__global__ __launch_bounds__(256) void gemm_qkv_k(
    const ushort* __restrict__ X,
    const ushort* __restrict__ Wq, const ushort* __restrict__ Wk, const ushort* __restrict__ Wv,
    ushort* __restrict__ Q, ushort* __restrict__ K, ushort* __restrict__ Vt)
{
  __shared__ __align__(16) ushort sh[17408];      // 34 KB: As|Bs (8K+8K), or 128x136 transpose
  ushort* As = sh;
  ushort* Bs = sh + 8192;
  const int z = blockIdx.z;
  const ushort* __restrict__ W = (z == 0) ? Wq : (z == 1) ? Wk : Wv;
  const int tid = threadIdx.x;
  const int wave = tid >> 6, lane = tid & 63;
  const int l15 = lane & 15, quad = lane >> 4;
  const int wm = wave >> 1, wn = wave & 1;
  const int m0 = blockIdx.y * 128;
  const int n0 = blockIdx.x * 128;

  f32x4 acc[4][4];
#pragma unroll
  for (int mi = 0; mi < 4; ++mi)
#pragma unroll
    for (int ni = 0; ni < 4; ++ni) acc[mi][ni] = (f32x4){0.f, 0.f, 0.f, 0.f};

  gemm_core(X, W, As, Bs, acc, m0, n0, wave, lane);

  if (z < 2) {
    ushort* dst = (z == 0) ? Q : K;
#pragma unroll
    for (int mi = 0; mi < 4; ++mi)
#pragma unroll
      for (int ni = 0; ni < 4; ++ni)
#pragma unroll
        for (int r = 0; r < 4; ++r) {
          int m = m0 + wm * 64 + mi * 16 + quad * 4 + r;   // token
          int n = n0 + wn * 64 + ni * 16 + l15;            // d_model col
          int b = m >> 11, s = m & (S_ - 1);
          int hh = n >> 6, dd = n & 63;
          dst[((size_t)(b * H_ + hh) * S_ + s) * DH_ + dd] = f2bf(acc[mi][ni][r]);
        }
  } else {
    // transpose through LDS -> coalesced b128 stores of V^T
    __syncthreads();
#pragma unroll
    for (int mi = 0; mi < 4; ++mi)
#pragma unroll
      for (int ni = 0; ni < 4; ++ni) {
        int n = wn * 64 + ni * 16 + l15;
        int m = wm * 64 + mi * 16 + quad * 4;
        ushort4 w4;
        w4.x = f2bf(acc[mi][ni][0]); w4.y = f2bf(acc[mi][ni][1]);
        w4.z = f2bf(acc[mi][ni][2]); w4.w = f2bf(acc[mi][ni][3]);
        *(ushort4*)&sh[n * 136 + m] = w4;                  // stride 136 -> conflict-light
      }
    __syncthreads();
    const int b = m0 >> 11, s0 = m0 & (S_ - 1);
#pragma unroll
    for (int p = 0; p < 8; ++p) {
      int task = p * 256 + tid;              // 128 n x 16 m-chunks
      int n = task >> 4, mc = (task & 15) * 8;
      int col = n0 + n, hh = col >> 6, dd = col & 63;
      *(short8*)(Vt + ((size_t)(b * H_ + hh) * DH_ + dd) * S_ + s0 + mc) =
          *(const short8*)&sh[n * 136 + mc];
    }
  }
}

// ---------------- Output projection: out = Ctx @ Wo^T (fp32) ----------------
__global__ __launch_bounds__(256) void gemm_out_k(
    const ushort* __restrict__ A, const ushort* __restrict__ W, float* __restrict__ out)
{
  __shared__ __align__(16) ushort sh[16384];
  ushort* As = sh;
  ushort* Bs = sh + 8192;
  const int tid = threadIdx.x;
  const int wave = tid >> 6, lane = tid & 63;
  const int l15 = lane & 15, quad = lane >> 4;
  const int wm = wave >> 1, wn = wave & 1;
  const int m0 = blockIdx.y * 128;
  const int n0 = blockIdx.x * 128;

  f32x4 acc[4][4];
#pragma unroll
  for (int mi = 0; mi < 4; ++mi)
#pragma unroll
    for (int ni = 0; ni < 4; ++ni) acc[mi][ni] = (f32x4){0.f, 0.f, 0.f, 0.f};

  gemm_core(A, W, As, Bs, acc, m0, n0, wave, lane);

#pragma unroll
  for (int mi = 0; mi < 4; ++mi)
#pragma unroll
    for (int ni = 0; ni < 4; ++ni)
#pragma unroll
      for (int r = 0; r < 4; ++r) {
        int m = m0 + wm * 64 + mi * 16 + quad * 4 + r;
        int n = n0 + wn * 64 + ni * 16 + l15;
        out[(size_t)m * DM_ + n] = acc[mi][ni][r];
      }
}

// ---------------- Flash attention: key-sliced waves, transposed QK, P in registers ----------------
// Block: 4 waves, 64 q-rows, 2048 keys in 64-key tiles; wave w owns key slice w*16..+16.
// S^T = K·Q^T puts P directly in PV A-operand layout (half-zero k=16 mfma) -> no LDS P.
// No online max (scores bounded; softmax shift-invariant). Row-sum via ones-MFMA.
// r7: bias read from GLOBAL (L2) premultiplied by 1/ln2 -> exp2(fma); P/V frags built
// as packed dwords via v_perm/unions (no 16-bit insertelement VALU storm).
// NOTE: epilogue loops must stay fully unrolled (runtime of[][] index => scratch spill, r5).
__global__ __launch_bounds__(256, 2) void attn_k(
    const ushort* __restrict__ Q, const ushort* __restrict__ K, const ushort* __restrict__ Vt,
    const float* __restrict__ biasTab, ushort* __restrict__ Ctx)
{
  __shared__ __align__(16) ushort KV[8192];   // Ks[64key][64dh] | Vs[64dh][64key], swizzled
  ushort* Ks = KV;
  ushort* Vs = KV + 4096;

  const int tid = threadIdx.x;
  const int wave = tid >> 6, lane = tid & 63;  // wave = key-slice id
  const int l15 = lane & 15, quad = lane >> 4;
  const int bh = blockIdx.y;
  const int h = bh & (H_ - 1);
  const int b = bh >> 4;
  const int qb = blockIdx.x * 64;
  const int srow = lane >> 3;
  const int sw = ((lane & 7) ^ (lane >> 3)) * 8;  // swizzled source col (elements)

  const f32x4 zero4 = {0.f, 0.f, 0.f, 0.f};

  const ushort* Qh = Q  + (size_t)bh * S_ * DH_;
  const ushort* Kh = K  + (size_t)bh * S_ * DH_;
  const ushort* Vh = Vt + (size_t)bh * DH_ * S_;

  // bias base: element (nf, r) at tile kt reads bp[kt - nf*16 + r]
  const float* bp = biasTab + h * NBIAS_ + 2047 - qb + wave * 16 + quad * 4 - l15;

  // Q B-frags: B[n=qrow=l15][k=dh], 64 rows x 64 dh -> 8 frags, kept in registers
  short8 qf[4][2];
#pragma unroll
  for (int nf = 0; nf < 4; ++nf)
#pragma unroll
    for (int kk = 0; kk < 2; ++kk)
      qf[nf][kk] = *(const short8*)(Qh + (size_t)(qb + nf * 16 + l15) * DH_ + kk * 32 + quad * 8);

  short8 oneh;                                 // {1,1,1,1,0,0,0,0} bf16
#pragma unroll
  for (int i = 0; i < 8; ++i) oneh[i] = (i < 4) ? (short)0x3F80 : (short)0;

  f32x4 of[4][4];                              // O[qrow nf][dh nt] partial
#pragma unroll
  for (int nf = 0; nf < 4; ++nf)
#pragma unroll
    for (int nt = 0; nt < 4; ++nt) of[nf][nt] = zero4;
  f32x4 ls[4];
#pragma unroll
  for (int nf = 0; nf < 4; ++nf) ls[nf] = zero4;

  const int kidx = (wave * 16 + l15) * 64;     // K row base (elements)
  const int vslot = wave * 2 + (quad >> 1);    // V logical 16B slot for this wave/quad

  for (int kt = 0; kt < S_; kt += 64) {
    __syncthreads();                           // prior tile's LDS reads done
#pragma unroll
    for (int i = 0; i < 2; ++i) {              // 16 chunks / 4 waves: K chunks 0..7, V 8..15
      int c = wave * 2 + i;
      ldg16_lds(Kh + (size_t)(kt + c * 8 + srow) * DH_ + sw, Ks + c * 512);
      ldg16_lds(Vh + (size_t)(c * 8 + srow) * S_ + kt + sw, Vs + c * 512);
    }
    __syncthreads();                           // drains vmcnt

    // ---- S^T = K·Q^T for this wave's 16 keys x 64 q-rows ----
    short8 kf0 = *(const short8*)&Ks[kidx + ((quad ^ (l15 & 7))) * 8];
    short8 kf1 = *(const short8*)&Ks[kidx + (((4 + quad) ^ (l15 & 7))) * 8];
    f32x4 sc[4];
#pragma unroll
    for (int nf = 0; nf < 4; ++nf) {
      sc[nf] = MFMA16(kf0, qf[nf][0], zero4);
      sc[nf] = MFMA16(kf1, qf[nf][1], sc[nf]);
    }

    // ---- p = exp2(s*c + b') straight into packed PV A-frags (perm-pack, no inserts) ----
    short8 pf[4];
#pragma unroll
    for (int nf = 0; nf < 4; ++nf) {
      const float* bnf = bp + kt - nf * 16;
      float p0 = exp2f(fmaf(sc[nf][0], LOG2E_DIV8, bnf[0]));
      float p1 = exp2f(fmaf(sc[nf][1], LOG2E_DIV8, bnf[1]));
      float p2 = exp2f(fmaf(sc[nf][2], LOG2E_DIV8, bnf[2]));
      float p3 = exp2f(fmaf(sc[nf][3], LOG2E_DIV8, bnf[3]));
      union { short8 v; unsigned u[4]; } P;
      P.u[0] = bpack(p1, p0);
      P.u[1] = bpack(p3, p2);
      P.u[2] = 0; P.u[3] = 0;
      pf[nf] = P.v;
    }

    // ---- row-sum + PV (half-zero k=16 mfma) ----
#pragma unroll
    for (int nf = 0; nf < 4; ++nf) ls[nf] = MFMA16(pf[nf], oneh, ls[nf]);
#pragma unroll
    for (int nt = 0; nt < 4; ++nt) {
      const uint2 v2 = *(const uint2*)&Vs[(nt * 16 + l15) * 64 +
                                          ((vslot ^ (l15 & 7))) * 8 + (quad & 1) * 4];
      union { short8 v; unsigned u[4]; } V;
      V.u[0] = v2.x; V.u[1] = v2.y; V.u[2] = 0; V.u[3] = 0;
      short8 vf = V.v;
#pragma unroll
      for (int nf = 0; nf < 4; ++nf)
        of[nf][nt] = MFMA16(pf[nf], vf, of[nf][nt]);
    }
  }

  // ---- cross-wave reduce (partials additive) + store. FULLY UNROLLED ----
  __syncthreads();
  float* red = (float*)KV;                     // 16 KB scratch (needs 16128 B)
#pragma unroll
  for (int mi = 0; mi < 4; ++mi) {
    if (wave) {
      int base = ((wave - 1) * 64 + lane) * 21;
#pragma unroll
      for (int nt = 0; nt < 4; ++nt)
#pragma unroll
        for (int r = 0; r < 4; ++r) red[base + nt * 4 + r] = of[mi][nt][r];
#pragma unroll
      for (int r = 0; r < 4; ++r) red[base + 16 + r] = ls[mi][r];
    }
    __syncthreads();
    if (wave == 0) {
#pragma unroll
      for (int w = 1; w < 4; ++w) {
        int base = ((w - 1) * 64 + lane) * 21;
#pragma unroll
        for (int nt = 0; nt < 4; ++nt)
#pragma unroll
          for (int r = 0; r < 4; ++r) of[mi][nt][r] += red[base + nt * 4 + r];
#pragma unroll
        for (int r = 0; r < 4; ++r) ls[mi][r] += red[base + 16 + r];
      }
#pragma unroll
      for (int nt = 0; nt < 4; ++nt)
#pragma unroll
        for (int r = 0; r < 4; ++r) {
          int t = b * S_ + qb + mi * 16 + quad * 4 + r;
          Ctx[(size_t)t * DM_ + h * 64 + nt * 16 + l15] = f2bf(of[mi][nt][r] / ls[mi][r]);
        }
    }
    __syncthreads();
  }
}

// ---------------- launch ----------------
extern "C" void kernel_launch(void* const* d_in, const int* in_sizes, int n_in,
                              void* d_out, int out_size, void* d_ws, size_t ws_size,
                              hipStream_t stream) {
  const float* hs  = (const float*)d_in[0];
  const float* Wq  = (const float*)d_in[1];
  const float* Wk  = (const float*)d_in[2];
  const float* Wv  = (const float*)d_in[3];
  const float* Wo  = (const float*)d_in[4];
  const float* rel = (const float*)d_in[5];
  float* out = (float*)d_out;

  ushort* Xb  = (ushort*)d_ws;                          // 4096x1024
  ushort* Wqb = Xb  + (size_t)NTOK_ * DM_;              // 1024x1024 each
  ushort* Wkb = Wqb + (size_t)DM_ * DM_;
  ushort* Wvb = Wkb + (size_t)DM_ * DM_;
  ushort* Wob = Wvb + (size_t)DM_ * DM_;
  ushort* Qd  = Wob + (size_t)DM_ * DM_;                // [b][h][s][dh]
  ushort* Kd  = Qd  + (size_t)NTOK_ * DM_;
  ushort* Vtd = Kd  + (size_t)NTOK_ * DM_;              // [b][h][dh][s]
  float* biasTab = (float*)(Vtd + (size_t)NTOK_ * DM_); // [H][4095], premul 1/ln2
  ushort* Ctx = Xb;                                     // alias: X dead after QKV GEMM

  prep_k<<<8208, 256, 0, stream>>>(hs, Wq, Wk, Wv, Wo, rel,
                                   Xb, Wqb, Wkb, Wvb, Wob, biasTab);
  gemm_qkv_k<<<dim3(8, 32, 3), 256, 0, stream>>>(Xb, Wqb, Wkb, Wvb, Qd, Kd, Vtd);
  attn_k<<<dim3(S_ / 64, 2 * H_), 256, 0, stream>>>(Qd, Kd, Vtd, biasTab, Ctx);
  gemm_out_k<<<dim3(8, 32), 256, 0, stream>>>(Ctx, Wob, out);
}